// Round 18
// baseline (179.471 us; speedup 1.0000x reference)
//
#include <hip/hip_runtime.h>
#include <hip/hip_bf16.h>

using bf16 = __hip_bfloat16;
typedef __attribute__((ext_vector_type(8))) short bf16x8;
typedef __attribute__((ext_vector_type(4))) short bf16x4;
typedef __attribute__((ext_vector_type(4))) float f32x4;

#define HIDDEN 512
#define HEADS 8
#define HDIM 64
#define INNER 2048
#define MAXD 512
#define BB 4
#define TT 2048
#define MM (BB*TT)   /* 8192 rows */
#define LOG2E 1.44269504088896340736f

typedef const __attribute__((address_space(1))) unsigned int* gas_u32p;
typedef __attribute__((address_space(3))) unsigned int* las_u32p;

__device__ __forceinline__ void gload_lds16(const void* g, void* l) {
    __builtin_amdgcn_global_load_lds((gas_u32p)g, (las_u32p)l, 16, 0, 0);
}
__device__ __forceinline__ short bfr(float x) {
    return (short)__bfloat16_as_ushort(__float2bfloat16(x));
}
__device__ __forceinline__ float bf2f(short u) {
    return __uint_as_float(((unsigned)(unsigned short)u) << 16);
}

// ---------------------------------------------------------------- fused prep: cast x + 4 weight transposes
__global__ __launch_bounds__(256) void prep_kernel(
    const float* __restrict__ x, const float* __restrict__ w_qkv,
    const float* __restrict__ w_out, const float* __restrict__ w1,
    const float* __restrict__ w2,
    bf16* __restrict__ xb, bf16* __restrict__ wqkv_t, bf16* __restrict__ wout_t,
    bf16* __restrict__ w1_t, bf16* __restrict__ w2_t)
{
    __shared__ float tile[32][33];
    int bid = blockIdx.x;
    if (bid < 4096) {                                // cast x -> bf16
        int i = (bid * 256 + threadIdx.x) * 4;
        float4 v = *(const float4*)&x[i];
        bf16 o[4] = {__float2bfloat16(v.x), __float2bfloat16(v.y),
                     __float2bfloat16(v.z), __float2bfloat16(v.w)};
        *(bf16x4*)&xb[i] = *(bf16x4*)o;
        return;
    }
    bid -= 4096;
    const float* in; bf16* out; int K, N, bx, by;
    if (bid < 768)       { in = w_qkv; out = wqkv_t; K = 512;  N = 1536; bx = bid % 48; by = bid / 48; }
    else if (bid < 1024) { bid -= 768;  in = w_out; out = wout_t; K = 512;  N = 512;  bx = bid % 16; by = bid / 16; }
    else if (bid < 2048) { bid -= 1024; in = w1;   out = w1_t;   K = 512;  N = 2048; bx = bid % 64; by = bid / 64; }
    else                 { bid -= 2048; in = w2;   out = w2_t;   K = 2048; N = 512;  bx = bid % 16; by = bid / 16; }
    int lx = threadIdx.x & 31, ly = threadIdx.x >> 5;   // 32 x 8
    #pragma unroll
    for (int i = 0; i < 4; ++i)
        tile[ly + 8*i][lx] = in[(size_t)(by*32 + ly + 8*i) * N + bx*32 + lx];
    __syncthreads();
    #pragma unroll
    for (int i = 0; i < 4; ++i)
        out[(size_t)(bx*32 + ly + 8*i) * K + by*32 + lx] =
            __float2bfloat16(tile[lx][ly + 8*i]);
}

// ---------------------------------------------------------------- MFMA GEMM, 2-phase prefetch double-buffer
// BN in {64,128}; 4 waves, each owning 64 x BN/2 of the 128 x BN tile.
// SPLITK: gridDim.z=2, block z computes K-half kz into C + kz*M*N (bias only z=1).
template<int EPI, int BN, int VT, int RESID, int SPLITK>
__global__ __launch_bounds__(256) void gemm_kernel(
    const bf16* __restrict__ A, const bf16* __restrict__ BT,
    const float* __restrict__ bias, const void* __restrict__ resid,
    bf16* __restrict__ C, bf16* __restrict__ vt_out,
    int M, int N, int K)
{
    constexpr int NBF = BN / 32;              // B-frags per wave (2/4)
    constexpr int NBS = BN / 64;              // B staging calls (1/2)
    constexpr int BBYTES = BN * 64;           // bytes per B buffer
    __shared__ __align__(16) bf16 As[2][128*32];
    __shared__ __align__(16) bf16 Bs[2][BN*32];
    const int tid = threadIdx.x;
    const int wid = tid >> 6;
    const int lane = tid & 63;
    const int lhi = lane >> 4, llo = lane & 15;
    const int m0 = blockIdx.x * 128, n0 = blockIdx.y * BN;
    const int wr = wid >> 1, wc = wid & 1;

    int kz = 0, KL = K;
    if (SPLITK) {
        kz = blockIdx.z;
        KL = K >> 1;
        A  += (size_t)kz * KL;
        BT += (size_t)kz * KL;
        C  += (size_t)kz * M * N;
    }

    const int srow = tid >> 2;
    const int scol = ((tid & 3) ^ ((srow >> 1) & 3)) * 8;
    const bf16* Ap = A + (size_t)(m0 + srow) * K + scol;
    const bf16* Bp = BT + (size_t)(n0 + srow) * K + scol;
    const size_t step64 = (size_t)64 * K;
    const int rsw = (llo >> 1) & 3;

    f32x4 acc[4][NBF] = {};

    auto STAGE = [&](int k1, int bi) {
        #pragma unroll
        for (int rr = 0; rr < 2; ++rr)
            gload_lds16(Ap + k1 + rr*step64, (char*)As + bi*8192 + rr*4096 + tid*16);
        #pragma unroll
        for (int rr = 0; rr < NBS; ++rr)
            gload_lds16(Bp + k1 + rr*step64, (char*)Bs + bi*BBYTES + rr*4096 + tid*16);
    };

    STAGE(0, 0);

    const int NK = KL >> 5;
    for (int it = 0; it < NK; ++it) {
        const int p = it & 1;
        __syncthreads();
        if (it + 1 < NK) STAGE((it + 1) << 5, p^1);
        bf16x8 af[4], bfrg[NBF];
        #pragma unroll
        for (int ar = 0; ar < 4; ++ar)
            af[ar] = *(const bf16x8*)((const char*)As + p*8192 +
                       (64*wr + 16*ar + llo)*64 + ((lhi ^ rsw) << 4));
        #pragma unroll
        for (int bc = 0; bc < NBF; ++bc)
            bfrg[bc] = *(const bf16x8*)((const char*)Bs + p*BBYTES +
                       ((BN/2)*wc + 16*bc + llo)*64 + ((lhi ^ rsw) << 4));
        #pragma unroll
        for (int ar = 0; ar < 4; ++ar)
            #pragma unroll
            for (int bc = 0; bc < NBF; ++bc)
                acc[ar][bc] = __builtin_amdgcn_mfma_f32_16x16x32_bf16(
                    af[ar], bfrg[bc], acc[ar][bc], 0, 0, 0);
    }

    if (VT && n0 >= 1024) {
        #pragma unroll
        for (int ar = 0; ar < 4; ++ar) {
            const int row = m0 + 64*wr + 16*ar + 4*lhi;
            const int bq = row >> 11, t0 = row & 2047;
            #pragma unroll
            for (int bc = 0; bc < NBF; ++bc) {
                const int cv = n0 - 1024 + (BN/2)*wc + 16*bc + llo;
                const int h = cv >> 6, d = cv & 63;
                float bv = bias[n0 + (BN/2)*wc + 16*bc + llo];
                bf16x4 pk = {bfr(acc[ar][bc][0] + bv), bfr(acc[ar][bc][1] + bv),
                             bfr(acc[ar][bc][2] + bv), bfr(acc[ar][bc][3] + bv)};
                *(bf16x4*)&vt_out[(((size_t)(bq*8 + h) * 64 + d) << 11) + t0] = pk;
            }
        }
        return;
    }

    #pragma unroll
    for (int ar = 0; ar < 4; ++ar) {
        #pragma unroll
        for (int j = 0; j < 4; ++j) {
            int row = m0 + 64*wr + 16*ar + 4*lhi + j;
            #pragma unroll
            for (int bc = 0; bc < NBF; ++bc) {
                int col = n0 + (BN/2)*wc + 16*bc + llo;
                float v = acc[ar][bc][j];
                if (!SPLITK || kz == 1) v += bias[col];
                if (RESID == 1)
                    v += ((const float*)resid)[(size_t)row * N + col];
                if (RESID == 2)
                    v += __bfloat162float(((const bf16*)resid)[(size_t)row * N + col]);
                if (EPI == 2) {
                    float u = 0.7978845608028654f * (v + 0.044715f * v * v * v);
                    float e = __builtin_amdgcn_exp2f(u * (2.0f * LOG2E));
                    v = v * (1.0f - 1.0f / (1.0f + e));
                }
                C[(size_t)row * N + col] = __float2bfloat16(v);
            }
        }
    }
}

// ---------------------------------------------------------------- flash attention, kv-split KVBLK=32
// (round-16/17 proven structure, unchanged)
#define PTN (TT + 128)
__global__ __launch_bounds__(512) void attn_kernel(
    const bf16* __restrict__ qkv,    // [B*T, 1536]
    const bf16* __restrict__ v_t,    // [B*H, 64, T]
    const float* __restrict__ rel_table,   // [1025, 8]
    bf16* __restrict__ attn_out)     // [B*T, 512]
{
    __shared__ __align__(16) char smem[49152 + PTN*4];
    char* KsB = smem;
    char* VsB = smem + 16384;
    char* PsB = smem + 32768;
    float* PT = (float*)(smem + 49152);

    const int qt = blockIdx.x, bh = blockIdx.y;
    const int b = bh >> 3, h = bh & 7;
    const int tid = threadIdx.x, wid = tid >> 6, lane = tid & 63;
    const int lhi = lane >> 4, llo = lane & 15;
    const int gw = wid >> 2;     // kv group (0/1)
    const int wq = wid & 3;      // q slot

    const int lo = qt*128 - (TT - 1);
    for (int i = tid; i < PTN; i += 512) {
        int idx = min(max(i + lo, -MAXD), MAXD) + MAXD;
        PT[i] = rel_table[(size_t)idx * HEADS + h] * LOG2E;
    }

    const int qb = qt * 128;
    const int q0w = qb + wq * 32;
    bf16x8 bq[2][2];
    #pragma unroll
    for (int qh = 0; qh < 2; ++qh)
        #pragma unroll
        for (int kc = 0; kc < 2; ++kc)
            bq[qh][kc] = *(const bf16x8*)&qkv[(size_t)(b*TT + q0w + qh*16 + llo) * 1536
                                              + h*64 + kc*32 + lhi*8];

    bf16x8 aones;
    #pragma unroll
    for (int i = 0; i < 8; ++i) aones[i] = (short)0x3F80;

    const int so = tid * 16;
    const int kg = so >> 12;
    const int kr = (so >> 7) & 31;
    const int kc0 = (((so & 127) ^ ((kr & 7) << 4)) >> 1);
    const int vd = (so >> 7) & 63;
    const int vbs = (so & 127) ^ ((vd & 7) << 4);
    const int vg = vbs >> 6;
    const int vke = (vbs & 63) >> 1;

    const bf16* kbase = qkv + (size_t)(b*TT) * 1536 + 512 + h*64;
    const bf16* vbase = v_t + (size_t)bh * 64 * TT;

    f32x4 accLf[2] = {};
    f32x4 accO[2][4] = {};

    gload_lds16(kbase + (size_t)(kg*32 + kr) * 1536 + kc0, KsB + so);
    gload_lds16(vbase + (size_t)vd * TT + vg*32 + vke,     VsB + so);
    __syncthreads();   // PT + tile0 ready

    const float cFut  = PT[min(max(-512 - lo, 0), PTN - 1)];
    const float cPast = PT[min(max( 512 - lo, 0), PTN - 1)];
    const float sc = 0.125f * LOG2E;
    const int ibq = wq*32 + llo + (TT - 1) - 4*lhi;

    for (int it = 0; it < 32; ++it) {
        const int p = it & 1;
        const int kv0 = it*64 + gw*32;
        if (it) __syncthreads();
        if (it + 1 < 32) {
            const int kn = (it + 1) * 64;
            gload_lds16(kbase + (size_t)(kn + kg*32 + kr) * 1536 + kc0, KsB + (p^1)*8192 + so);
            gload_lds16(vbase + (size_t)vd * TT + kn + vg*32 + vke,     VsB + (p^1)*8192 + so);
        }
        const char* Kb = KsB + p*8192 + gw*4096;
        const char* Vb = VsB + p*8192;

        // S^T[kv][q] = mfma(A=K, B=Q)
        f32x4 s[2][2] = {};
        __builtin_amdgcn_s_setprio(1);
        #pragma unroll
        for (int f = 0; f < 2; ++f) {
            const int rr = 16*f + llo;
            #pragma unroll
            for (int kc = 0; kc < 2; ++kc) {
                bf16x8 ak = *(const bf16x8*)(Kb + rr*128 + (((4*kc + lhi) ^ (rr & 7)) << 4));
                #pragma unroll
                for (int qh = 0; qh < 2; ++qh)
                    s[qh][f] = __builtin_amdgcn_mfma_f32_16x16x32_bf16(
                        ak, bq[qh][kc], s[qh][f], 0, 0, 0);
            }
        }
        __builtin_amdgcn_s_setprio(0);

        // bias (exp2 domain): wave-uniform far-tile constants
        if (kv0 >= qb + 639) {
            #pragma unroll
            for (int qh = 0; qh < 2; ++qh)
                #pragma unroll
                for (int f = 0; f < 2; ++f)
                    #pragma unroll
                    for (int j = 0; j < 4; ++j)
                        s[qh][f][j] = fmaf(s[qh][f][j], sc, cFut);
        } else if (kv0 <= qb - 543) {
            #pragma unroll
            for (int qh = 0; qh < 2; ++qh)
                #pragma unroll
                for (int f = 0; f < 2; ++f)
                    #pragma unroll
                    for (int j = 0; j < 4; ++j)
                        s[qh][f][j] = fmaf(s[qh][f][j], sc, cPast);
        } else {
            const int ib = ibq - kv0;
            #pragma unroll
            for (int qh = 0; qh < 2; ++qh)
                #pragma unroll
                for (int f = 0; f < 2; ++f)
                    #pragma unroll
                    for (int j = 0; j < 4; ++j)
                        s[qh][f][j] = fmaf(s[qh][f][j], sc, PT[ib + qh*16 - 16*f - j]);
        }

        // exp2 + pack P^T
        #pragma unroll
        for (int qh = 0; qh < 2; ++qh) {
            #pragma unroll
            for (int f = 0; f < 2; ++f) {
                float p0 = __builtin_amdgcn_exp2f(s[qh][f][0]);
                float p1 = __builtin_amdgcn_exp2f(s[qh][f][1]);
                float p2 = __builtin_amdgcn_exp2f(s[qh][f][2]);
                float p3 = __builtin_amdgcn_exp2f(s[qh][f][3]);
                bf16x4 pk = {bfr(p0), bfr(p1), bfr(p2), bfr(p3)};
                *(bf16x4*)(PsB + wid*2048 + llo*128 +
                           ((qh*64 + f*32 + lhi*8) ^ ((llo & 7) << 4))) = pk;
            }
        }

        // O^T[d][q] += mfma(A=V^T, B=P^T) ; l += mfma(A=1, B=P^T)
        bf16x8 pf[2];
        #pragma unroll
        for (int qh = 0; qh < 2; ++qh)
            pf[qh] = *(const bf16x8*)(PsB + wid*2048 + llo*128 +
                                      ((qh*64 + lhi*16) ^ ((llo & 7) << 4)));
        __builtin_amdgcn_s_setprio(1);
        #pragma unroll
        for (int fd = 0; fd < 4; ++fd) {
            const int rv = 16*fd + llo;
            bf16x8 av = *(const bf16x8*)(Vb + rv*128 +
                         ((gw*64 + lhi*16) ^ ((rv & 7) << 4)));
            #pragma unroll
            for (int qh = 0; qh < 2; ++qh)
                accO[qh][fd] = __builtin_amdgcn_mfma_f32_16x16x32_bf16(
                    av, pf[qh], accO[qh][fd], 0, 0, 0);
        }
        #pragma unroll
        for (int qh = 0; qh < 2; ++qh)
            accLf[qh] = __builtin_amdgcn_mfma_f32_16x16x32_bf16(
                aones, pf[qh], accLf[qh], 0, 0, 0);
        __builtin_amdgcn_s_setprio(0);
    }

    // cross-group combine (O = O_g0 + O_g1, l = l_g0 + l_g1)
    __syncthreads();
    float* xbuf = (float*)smem;
    if (gw == 1) {
        float* dst = xbuf + (size_t)(wq*64 + lane) * 34;
        #pragma unroll
        for (int qh = 0; qh < 2; ++qh)
            #pragma unroll
            for (int fd = 0; fd < 4; ++fd)
                #pragma unroll
                for (int j = 0; j < 4; ++j)
                    dst[qh*16 + fd*4 + j] = accO[qh][fd][j];
        dst[32] = accLf[0][0]; dst[33] = accLf[1][0];
    }
    __syncthreads();
    if (gw == 0) {
        const float* src = xbuf + (size_t)(wq*64 + lane) * 34;
        #pragma unroll
        for (int qh = 0; qh < 2; ++qh) {
            const float rl = 1.0f / (accLf[qh][0] + src[32 + qh]);
            const int row = b*TT + q0w + qh*16 + llo;
            #pragma unroll
            for (int fd = 0; fd < 4; ++fd) {
                bf16x4 ov = {bfr((accO[qh][fd][0] + src[qh*16 + fd*4 + 0]) * rl),
                             bfr((accO[qh][fd][1] + src[qh*16 + fd*4 + 1]) * rl),
                             bfr((accO[qh][fd][2] + src[qh*16 + fd*4 + 2]) * rl),
                             bfr((accO[qh][fd][3] + src[qh*16 + fd*4 + 3]) * rl)};
                *(bf16x4*)&attn_out[(size_t)row * HIDDEN + h*64 + 16*fd + 4*lhi] = ov;
            }
        }
    }
}

// ---------------------------------------------------------------- LayerNorm over sum of 3 bf16 streams
// WB=1: write bf16; WB=0: write f32.
template<int WB>
__global__ __launch_bounds__(256) void ln3_kernel(
    const bf16* __restrict__ in0, const bf16* __restrict__ in1,
    const bf16* __restrict__ in2,
    const float* __restrict__ g, const float* __restrict__ bb,
    float* __restrict__ of, bf16* __restrict__ ob)
{
    int row = blockIdx.x * 4 + (threadIdx.x >> 6);
    int lane = threadIdx.x & 63;
    const size_t off = (size_t)row * HIDDEN + lane * 8;
    bf16x8 a8 = *(const bf16x8*)&in0[off];
    bf16x8 b8 = *(const bf16x8*)&in1[off];
    bf16x8 c8 = *(const bf16x8*)&in2[off];
    float v[8];
    float s = 0.f, sq = 0.f;
    #pragma unroll
    for (int j = 0; j < 8; ++j) {
        v[j] = bf2f(a8[j]) + bf2f(b8[j]) + bf2f(c8[j]);
        s += v[j]; sq += v[j] * v[j];
    }
    #pragma unroll
    for (int d = 1; d < 64; d <<= 1) {
        s  += __shfl_xor(s,  d, 64);
        sq += __shfl_xor(sq, d, 64);
    }
    float mean = s * (1.f / HIDDEN);
    float var  = sq * (1.f / HIDDEN) - mean * mean;
    float rstd = rsqrtf(var + 1e-5f);
    float o[8];
    #pragma unroll
    for (int j = 0; j < 8; ++j) {
        int col = lane * 8 + j;
        o[j] = (v[j] - mean) * rstd * g[col] + bb[col];
    }
    if (WB) {
        bf16x8 ov;
        #pragma unroll
        for (int j = 0; j < 8; ++j) ov[j] = bfr(o[j]);
        *(bf16x8*)&ob[off] = ov;
    } else {
        float4 o0 = {o[0], o[1], o[2], o[3]};
        float4 o1 = {o[4], o[5], o[6], o[7]};
        *(float4*)&of[off]     = o0;
        *(float4*)&of[off + 4] = o1;
    }
}

// ---------------------------------------------------------------- launcher
extern "C" void kernel_launch(void* const* d_in, const int* in_sizes, int n_in,
                              void* d_out, int out_size, void* d_ws, size_t ws_size,
                              hipStream_t stream) {
    const float* x     = (const float*)d_in[0];
    const float* w_qkv = (const float*)d_in[1];
    const float* b_qkv = (const float*)d_in[2];
    const float* w_out = (const float*)d_in[3];
    const float* b_out = (const float*)d_in[4];
    const float* ln1_g = (const float*)d_in[5];
    const float* ln1_b = (const float*)d_in[6];
    const float* ln2_g = (const float*)d_in[7];
    const float* ln2_b = (const float*)d_in[8];
    const float* w1    = (const float*)d_in[9];
    const float* b1    = (const float*)d_in[10];
    const float* w2    = (const float*)d_in[11];
    const float* b2    = (const float*)d_in[12];
    const float* rel   = (const float*)d_in[13];
    float* out = (float*)d_out;

    char* ws = (char*)d_ws;
    bf16*  xb     = (bf16*)(ws + 0);
    bf16*  wqkv_t = (bf16*)(ws + 8388608);
    bf16*  wout_t = (bf16*)(ws + 9961472);
    bf16*  w1_t   = (bf16*)(ws + 10485760);
    bf16*  w2_t   = (bf16*)(ws + 12582912);
    bf16*  qkv    = (bf16*)(ws + 14680064);
    bf16*  v_t    = (bf16*)(ws + 39845888);
    bf16*  attn_o = (bf16*)(ws + 48234496);
    bf16*  proj   = (bf16*)(ws + 56623104);   // p0; p1 follows contiguously
    bf16*  h      = (bf16*)(ws + 14680064);   // reuses qkv+v_t (dead after attention)
    bf16*  x1b    = (bf16*)(ws + 90177536);

    // 1. fused prep: cast + all weight transposes
    prep_kernel<<<7168, 256, 0, stream>>>(x, w_qkv, w_out, w1, w2,
                                          xb, wqkv_t, wout_t, w1_t, w2_t);
    // 2. qkv projection (V blocks write v_t directly)
    gemm_kernel<0,128,1,0,0><<<dim3(MM/128, 1536/128), 256, 0, stream>>>(
        xb, wqkv_t, b_qkv, nullptr, qkv, v_t, MM, 1536, 512);
    // 3. flash attention (128 q-rows per block, 2 kv-groups x 4 waves x 32q)
    attn_kernel<<<dim3(TT/128, BB*HEADS), 512, 0, stream>>>(qkv, v_t, rel, attn_o);
    // 4. output projection, split-K x2 -> bf16 partials p0/p1 (bias in z=1)
    gemm_kernel<0,64,0,0,1><<<dim3(MM/128, 512/64, 2), 256, 0, stream>>>(
        attn_o, wout_t, b_out, nullptr, proj, nullptr, MM, 512, 512);
    // 5. LN1 over (xb + p0 + p1) -> x1b (bf16)
    ln3_kernel<1><<<MM/4, 256, 0, stream>>>(xb, proj, proj + (size_t)MM*512,
                                            ln1_g, ln1_b, nullptr, x1b);
    // 6. MLP up + GELU(tanh) -> h (bf16), 128x128 tile
    gemm_kernel<2,128,0,0,0><<<dim3(MM/128, 2048/128), 256, 0, stream>>>(
        x1b, w1_t, b1, nullptr, h, nullptr, MM, 2048, 512);
    // 7. MLP down, split-K x2 -> bf16 partials p0/p1 (bias in z=1)
    gemm_kernel<0,64,0,0,1><<<dim3(MM/128, 512/64, 2), 256, 0, stream>>>(
        h, w2_t, b2, nullptr, proj, nullptr, MM, 512, 2048);
    // 8. LN2 over (x1b + p0 + p1) -> output (f32)
    ln3_kernel<0><<<MM/4, 256, 0, stream>>>(x1b, proj, proj + (size_t)MM*512,
                                            ln2_g, ln2_b, out, nullptr);
}

// Round 19
// 175.225 us; speedup vs baseline: 1.0242x; 1.0242x over previous
//
#include <hip/hip_runtime.h>
#include <hip/hip_bf16.h>

using bf16 = __hip_bfloat16;
typedef __attribute__((ext_vector_type(8))) short bf16x8;
typedef __attribute__((ext_vector_type(4))) short bf16x4;
typedef __attribute__((ext_vector_type(4))) float f32x4;

#define HIDDEN 512
#define HEADS 8
#define HDIM 64
#define INNER 2048
#define MAXD 512
#define BB 4
#define TT 2048
#define MM (BB*TT)   /* 8192 rows */
#define LOG2E 1.44269504088896340736f

typedef const __attribute__((address_space(1))) unsigned int* gas_u32p;
typedef __attribute__((address_space(3))) unsigned int* las_u32p;

__device__ __forceinline__ void gload_lds16(const void* g, void* l) {
    __builtin_amdgcn_global_load_lds((gas_u32p)g, (las_u32p)l, 16, 0, 0);
}
__device__ __forceinline__ short bfr(float x) {
    return (short)__bfloat16_as_ushort(__float2bfloat16(x));
}
__device__ __forceinline__ float bf2f(short u) {
    return __uint_as_float(((unsigned)(unsigned short)u) << 16);
}

// ---------------------------------------------------------------- fused prep: cast x + 4 weight transposes
__global__ __launch_bounds__(256) void prep_kernel(
    const float* __restrict__ x, const float* __restrict__ w_qkv,
    const float* __restrict__ w_out, const float* __restrict__ w1,
    const float* __restrict__ w2,
    bf16* __restrict__ xb, bf16* __restrict__ wqkv_t, bf16* __restrict__ wout_t,
    bf16* __restrict__ w1_t, bf16* __restrict__ w2_t)
{
    __shared__ float tile[32][33];
    int bid = blockIdx.x;
    if (bid < 4096) {                                // cast x -> bf16
        int i = (bid * 256 + threadIdx.x) * 4;
        float4 v = *(const float4*)&x[i];
        bf16 o[4] = {__float2bfloat16(v.x), __float2bfloat16(v.y),
                     __float2bfloat16(v.z), __float2bfloat16(v.w)};
        *(bf16x4*)&xb[i] = *(bf16x4*)o;
        return;
    }
    bid -= 4096;
    const float* in; bf16* out; int K, N, bx, by;
    if (bid < 768)       { in = w_qkv; out = wqkv_t; K = 512;  N = 1536; bx = bid % 48; by = bid / 48; }
    else if (bid < 1024) { bid -= 768;  in = w_out; out = wout_t; K = 512;  N = 512;  bx = bid % 16; by = bid / 16; }
    else if (bid < 2048) { bid -= 1024; in = w1;   out = w1_t;   K = 512;  N = 2048; bx = bid % 64; by = bid / 64; }
    else                 { bid -= 2048; in = w2;   out = w2_t;   K = 2048; N = 512;  bx = bid % 16; by = bid / 16; }
    int lx = threadIdx.x & 31, ly = threadIdx.x >> 5;   // 32 x 8
    #pragma unroll
    for (int i = 0; i < 4; ++i)
        tile[ly + 8*i][lx] = in[(size_t)(by*32 + ly + 8*i) * N + bx*32 + lx];
    __syncthreads();
    #pragma unroll
    for (int i = 0; i < 4; ++i)
        out[(size_t)(bx*32 + ly + 8*i) * K + by*32 + lx] =
            __float2bfloat16(tile[lx][ly + 8*i]);
}

// ---------------------------------------------------------------- MFMA GEMM, 2-phase prefetch double-buffer
// BN in {64,128}; 4 waves, each owning 64 x BN/2 of the 128 x BN tile.
// SPLITK: gridDim.z=2, block z computes K-half kz into C + kz*M*N (bias only z=1).
template<int EPI, int BN, int VT, int RESID, int SPLITK>
__global__ __launch_bounds__(256) void gemm_kernel(
    const bf16* __restrict__ A, const bf16* __restrict__ BT,
    const float* __restrict__ bias, const void* __restrict__ resid,
    bf16* __restrict__ C, bf16* __restrict__ vt_out,
    int M, int N, int K)
{
    constexpr int NBF = BN / 32;              // B-frags per wave (2/4)
    constexpr int NBS = BN / 64;              // B staging calls (1/2)
    constexpr int BBYTES = BN * 64;           // bytes per B buffer
    __shared__ __align__(16) bf16 As[2][128*32];
    __shared__ __align__(16) bf16 Bs[2][BN*32];
    const int tid = threadIdx.x;
    const int wid = tid >> 6;
    const int lane = tid & 63;
    const int lhi = lane >> 4, llo = lane & 15;
    const int m0 = blockIdx.x * 128, n0 = blockIdx.y * BN;
    const int wr = wid >> 1, wc = wid & 1;

    int kz = 0, KL = K;
    if (SPLITK) {
        kz = blockIdx.z;
        KL = K >> 1;
        A  += (size_t)kz * KL;
        BT += (size_t)kz * KL;
        C  += (size_t)kz * M * N;
    }

    const int srow = tid >> 2;
    const int scol = ((tid & 3) ^ ((srow >> 1) & 3)) * 8;
    const bf16* Ap = A + (size_t)(m0 + srow) * K + scol;
    const bf16* Bp = BT + (size_t)(n0 + srow) * K + scol;
    const size_t step64 = (size_t)64 * K;
    const int rsw = (llo >> 1) & 3;

    f32x4 acc[4][NBF] = {};

    auto STAGE = [&](int k1, int bi) {
        #pragma unroll
        for (int rr = 0; rr < 2; ++rr)
            gload_lds16(Ap + k1 + rr*step64, (char*)As + bi*8192 + rr*4096 + tid*16);
        #pragma unroll
        for (int rr = 0; rr < NBS; ++rr)
            gload_lds16(Bp + k1 + rr*step64, (char*)Bs + bi*BBYTES + rr*4096 + tid*16);
    };

    STAGE(0, 0);

    const int NK = KL >> 5;
    for (int it = 0; it < NK; ++it) {
        const int p = it & 1;
        __syncthreads();
        if (it + 1 < NK) STAGE((it + 1) << 5, p^1);
        bf16x8 af[4], bfrg[NBF];
        #pragma unroll
        for (int ar = 0; ar < 4; ++ar)
            af[ar] = *(const bf16x8*)((const char*)As + p*8192 +
                       (64*wr + 16*ar + llo)*64 + ((lhi ^ rsw) << 4));
        #pragma unroll
        for (int bc = 0; bc < NBF; ++bc)
            bfrg[bc] = *(const bf16x8*)((const char*)Bs + p*BBYTES +
                       ((BN/2)*wc + 16*bc + llo)*64 + ((lhi ^ rsw) << 4));
        #pragma unroll
        for (int ar = 0; ar < 4; ++ar)
            #pragma unroll
            for (int bc = 0; bc < NBF; ++bc)
                acc[ar][bc] = __builtin_amdgcn_mfma_f32_16x16x32_bf16(
                    af[ar], bfrg[bc], acc[ar][bc], 0, 0, 0);
    }

    if (VT && n0 >= 1024) {
        #pragma unroll
        for (int ar = 0; ar < 4; ++ar) {
            const int row = m0 + 64*wr + 16*ar + 4*lhi;
            const int bq = row >> 11, t0 = row & 2047;
            #pragma unroll
            for (int bc = 0; bc < NBF; ++bc) {
                const int cv = n0 - 1024 + (BN/2)*wc + 16*bc + llo;
                const int h = cv >> 6, d = cv & 63;
                float bv = bias[n0 + (BN/2)*wc + 16*bc + llo];
                bf16x4 pk = {bfr(acc[ar][bc][0] + bv), bfr(acc[ar][bc][1] + bv),
                             bfr(acc[ar][bc][2] + bv), bfr(acc[ar][bc][3] + bv)};
                *(bf16x4*)&vt_out[(((size_t)(bq*8 + h) * 64 + d) << 11) + t0] = pk;
            }
        }
        return;
    }

    #pragma unroll
    for (int ar = 0; ar < 4; ++ar) {
        #pragma unroll
        for (int j = 0; j < 4; ++j) {
            int row = m0 + 64*wr + 16*ar + 4*lhi + j;
            #pragma unroll
            for (int bc = 0; bc < NBF; ++bc) {
                int col = n0 + (BN/2)*wc + 16*bc + llo;
                float v = acc[ar][bc][j];
                if (!SPLITK || kz == 1) v += bias[col];
                if (RESID == 1)
                    v += ((const float*)resid)[(size_t)row * N + col];
                if (RESID == 2)
                    v += __bfloat162float(((const bf16*)resid)[(size_t)row * N + col]);
                if (EPI == 2) {
                    float u = 0.7978845608028654f * (v + 0.044715f * v * v * v);
                    float e = __builtin_amdgcn_exp2f(u * (2.0f * LOG2E));
                    v = v * (1.0f - 1.0f / (1.0f + e));
                }
                C[(size_t)row * N + col] = __float2bfloat16(v);
            }
        }
    }
}

// ---------------------------------------------------------------- flash attention, kv-split KVBLK=32
// (round-16/17 proven structure, unchanged)
#define PTN (TT + 128)
__global__ __launch_bounds__(512) void attn_kernel(
    const bf16* __restrict__ qkv,    // [B*T, 1536]
    const bf16* __restrict__ v_t,    // [B*H, 64, T]
    const float* __restrict__ rel_table,   // [1025, 8]
    bf16* __restrict__ attn_out)     // [B*T, 512]
{
    __shared__ __align__(16) char smem[49152 + PTN*4];
    char* KsB = smem;
    char* VsB = smem + 16384;
    char* PsB = smem + 32768;
    float* PT = (float*)(smem + 49152);

    const int qt = blockIdx.x, bh = blockIdx.y;
    const int b = bh >> 3, h = bh & 7;
    const int tid = threadIdx.x, wid = tid >> 6, lane = tid & 63;
    const int lhi = lane >> 4, llo = lane & 15;
    const int gw = wid >> 2;     // kv group (0/1)
    const int wq = wid & 3;      // q slot

    const int lo = qt*128 - (TT - 1);
    for (int i = tid; i < PTN; i += 512) {
        int idx = min(max(i + lo, -MAXD), MAXD) + MAXD;
        PT[i] = rel_table[(size_t)idx * HEADS + h] * LOG2E;
    }

    const int qb = qt * 128;
    const int q0w = qb + wq * 32;
    bf16x8 bq[2][2];
    #pragma unroll
    for (int qh = 0; qh < 2; ++qh)
        #pragma unroll
        for (int kc = 0; kc < 2; ++kc)
            bq[qh][kc] = *(const bf16x8*)&qkv[(size_t)(b*TT + q0w + qh*16 + llo) * 1536
                                              + h*64 + kc*32 + lhi*8];

    bf16x8 aones;
    #pragma unroll
    for (int i = 0; i < 8; ++i) aones[i] = (short)0x3F80;

    const int so = tid * 16;
    const int kg = so >> 12;
    const int kr = (so >> 7) & 31;
    const int kc0 = (((so & 127) ^ ((kr & 7) << 4)) >> 1);
    const int vd = (so >> 7) & 63;
    const int vbs = (so & 127) ^ ((vd & 7) << 4);
    const int vg = vbs >> 6;
    const int vke = (vbs & 63) >> 1;

    const bf16* kbase = qkv + (size_t)(b*TT) * 1536 + 512 + h*64;
    const bf16* vbase = v_t + (size_t)bh * 64 * TT;

    f32x4 accLf[2] = {};
    f32x4 accO[2][4] = {};

    gload_lds16(kbase + (size_t)(kg*32 + kr) * 1536 + kc0, KsB + so);
    gload_lds16(vbase + (size_t)vd * TT + vg*32 + vke,     VsB + so);
    __syncthreads();   // PT + tile0 ready

    const float cFut  = PT[min(max(-512 - lo, 0), PTN - 1)];
    const float cPast = PT[min(max( 512 - lo, 0), PTN - 1)];
    const float sc = 0.125f * LOG2E;
    const int ibq = wq*32 + llo + (TT - 1) - 4*lhi;

    for (int it = 0; it < 32; ++it) {
        const int p = it & 1;
        const int kv0 = it*64 + gw*32;
        if (it) __syncthreads();
        if (it + 1 < 32) {
            const int kn = (it + 1) * 64;
            gload_lds16(kbase + (size_t)(kn + kg*32 + kr) * 1536 + kc0, KsB + (p^1)*8192 + so);
            gload_lds16(vbase + (size_t)vd * TT + kn + vg*32 + vke,     VsB + (p^1)*8192 + so);
        }
        const char* Kb = KsB + p*8192 + gw*4096;
        const char* Vb = VsB + p*8192;

        // S^T[kv][q] = mfma(A=K, B=Q)
        f32x4 s[2][2] = {};
        __builtin_amdgcn_s_setprio(1);
        #pragma unroll
        for (int f = 0; f < 2; ++f) {
            const int rr = 16*f + llo;
            #pragma unroll
            for (int kc = 0; kc < 2; ++kc) {
                bf16x8 ak = *(const bf16x8*)(Kb + rr*128 + (((4*kc + lhi) ^ (rr & 7)) << 4));
                #pragma unroll
                for (int qh = 0; qh < 2; ++qh)
                    s[qh][f] = __builtin_amdgcn_mfma_f32_16x16x32_bf16(
                        ak, bq[qh][kc], s[qh][f], 0, 0, 0);
            }
        }
        __builtin_amdgcn_s_setprio(0);

        // bias (exp2 domain): wave-uniform far-tile constants
        if (kv0 >= qb + 639) {
            #pragma unroll
            for (int qh = 0; qh < 2; ++qh)
                #pragma unroll
                for (int f = 0; f < 2; ++f)
                    #pragma unroll
                    for (int j = 0; j < 4; ++j)
                        s[qh][f][j] = fmaf(s[qh][f][j], sc, cFut);
        } else if (kv0 <= qb - 543) {
            #pragma unroll
            for (int qh = 0; qh < 2; ++qh)
                #pragma unroll
                for (int f = 0; f < 2; ++f)
                    #pragma unroll
                    for (int j = 0; j < 4; ++j)
                        s[qh][f][j] = fmaf(s[qh][f][j], sc, cPast);
        } else {
            const int ib = ibq - kv0;
            #pragma unroll
            for (int qh = 0; qh < 2; ++qh)
                #pragma unroll
                for (int f = 0; f < 2; ++f)
                    #pragma unroll
                    for (int j = 0; j < 4; ++j)
                        s[qh][f][j] = fmaf(s[qh][f][j], sc, PT[ib + qh*16 - 16*f - j]);
        }

        // exp2 + pack P^T
        #pragma unroll
        for (int qh = 0; qh < 2; ++qh) {
            #pragma unroll
            for (int f = 0; f < 2; ++f) {
                float p0 = __builtin_amdgcn_exp2f(s[qh][f][0]);
                float p1 = __builtin_amdgcn_exp2f(s[qh][f][1]);
                float p2 = __builtin_amdgcn_exp2f(s[qh][f][2]);
                float p3 = __builtin_amdgcn_exp2f(s[qh][f][3]);
                bf16x4 pk = {bfr(p0), bfr(p1), bfr(p2), bfr(p3)};
                *(bf16x4*)(PsB + wid*2048 + llo*128 +
                           ((qh*64 + f*32 + lhi*8) ^ ((llo & 7) << 4))) = pk;
            }
        }

        // O^T[d][q] += mfma(A=V^T, B=P^T) ; l += mfma(A=1, B=P^T)
        bf16x8 pf[2];
        #pragma unroll
        for (int qh = 0; qh < 2; ++qh)
            pf[qh] = *(const bf16x8*)(PsB + wid*2048 + llo*128 +
                                      ((qh*64 + lhi*16) ^ ((llo & 7) << 4)));
        __builtin_amdgcn_s_setprio(1);
        #pragma unroll
        for (int fd = 0; fd < 4; ++fd) {
            const int rv = 16*fd + llo;
            bf16x8 av = *(const bf16x8*)(Vb + rv*128 +
                         ((gw*64 + lhi*16) ^ ((rv & 7) << 4)));
            #pragma unroll
            for (int qh = 0; qh < 2; ++qh)
                accO[qh][fd] = __builtin_amdgcn_mfma_f32_16x16x32_bf16(
                    av, pf[qh], accO[qh][fd], 0, 0, 0);
        }
        #pragma unroll
        for (int qh = 0; qh < 2; ++qh)
            accLf[qh] = __builtin_amdgcn_mfma_f32_16x16x32_bf16(
                aones, pf[qh], accLf[qh], 0, 0, 0);
        __builtin_amdgcn_s_setprio(0);
    }

    // cross-group combine (O = O_g0 + O_g1, l = l_g0 + l_g1)
    __syncthreads();
    float* xbuf = (float*)smem;
    if (gw == 1) {
        float* dst = xbuf + (size_t)(wq*64 + lane) * 34;
        #pragma unroll
        for (int qh = 0; qh < 2; ++qh)
            #pragma unroll
            for (int fd = 0; fd < 4; ++fd)
                #pragma unroll
                for (int j = 0; j < 4; ++j)
                    dst[qh*16 + fd*4 + j] = accO[qh][fd][j];
        dst[32] = accLf[0][0]; dst[33] = accLf[1][0];
    }
    __syncthreads();
    if (gw == 0) {
        const float* src = xbuf + (size_t)(wq*64 + lane) * 34;
        #pragma unroll
        for (int qh = 0; qh < 2; ++qh) {
            const float rl = 1.0f / (accLf[qh][0] + src[32 + qh]);
            const int row = b*TT + q0w + qh*16 + llo;
            #pragma unroll
            for (int fd = 0; fd < 4; ++fd) {
                bf16x4 ov = {bfr((accO[qh][fd][0] + src[qh*16 + fd*4 + 0]) * rl),
                             bfr((accO[qh][fd][1] + src[qh*16 + fd*4 + 1]) * rl),
                             bfr((accO[qh][fd][2] + src[qh*16 + fd*4 + 2]) * rl),
                             bfr((accO[qh][fd][3] + src[qh*16 + fd*4 + 3]) * rl)};
                *(bf16x4*)&attn_out[(size_t)row * HIDDEN + h*64 + 16*fd + 4*lhi] = ov;
            }
        }
    }
}

// ---------------------------------------------------------------- LayerNorm, bf16 input (residual pre-added)
template<int WB>
__global__ __launch_bounds__(256) void ln_kernel(
    const bf16* __restrict__ in,
    const float* __restrict__ g, const float* __restrict__ bb,
    float* __restrict__ of, bf16* __restrict__ ob)
{
    int row = blockIdx.x * 4 + (threadIdx.x >> 6);
    int lane = threadIdx.x & 63;
    const bf16* pa = in + (size_t)row * HIDDEN + lane * 8;
    bf16x8 v8 = *(const bf16x8*)pa;
    float v[8];
    float s = 0.f, sq = 0.f;
    #pragma unroll
    for (int j = 0; j < 8; ++j) {
        v[j] = bf2f(v8[j]);
        s += v[j]; sq += v[j] * v[j];
    }
    #pragma unroll
    for (int d = 1; d < 64; d <<= 1) {
        s  += __shfl_xor(s,  d, 64);
        sq += __shfl_xor(sq, d, 64);
    }
    float mean = s * (1.f / HIDDEN);
    float var  = sq * (1.f / HIDDEN) - mean * mean;
    float rstd = rsqrtf(var + 1e-5f);
    float o[8];
    #pragma unroll
    for (int j = 0; j < 8; ++j) {
        int col = lane * 8 + j;
        o[j] = (v[j] - mean) * rstd * g[col] + bb[col];
    }
    if (WB) {
        bf16x8 ov;
        #pragma unroll
        for (int j = 0; j < 8; ++j) ov[j] = bfr(o[j]);
        *(bf16x8*)&ob[(size_t)row * HIDDEN + lane * 8] = ov;
    } else {
        float4 o0 = {o[0], o[1], o[2], o[3]};
        float4 o1 = {o[4], o[5], o[6], o[7]};
        *(float4*)&of[(size_t)row * HIDDEN + lane * 8]     = o0;
        *(float4*)&of[(size_t)row * HIDDEN + lane * 8 + 4] = o1;
    }
}

// ---------------------------------------------------------------- LayerNorm over sum of 3 bf16 streams -> f32 out
__global__ __launch_bounds__(256) void ln3_kernel(
    const bf16* __restrict__ in0, const bf16* __restrict__ in1,
    const bf16* __restrict__ in2,
    const float* __restrict__ g, const float* __restrict__ bb,
    float* __restrict__ of)
{
    int row = blockIdx.x * 4 + (threadIdx.x >> 6);
    int lane = threadIdx.x & 63;
    const size_t off = (size_t)row * HIDDEN + lane * 8;
    bf16x8 a8 = *(const bf16x8*)&in0[off];
    bf16x8 b8 = *(const bf16x8*)&in1[off];
    bf16x8 c8 = *(const bf16x8*)&in2[off];
    float v[8];
    float s = 0.f, sq = 0.f;
    #pragma unroll
    for (int j = 0; j < 8; ++j) {
        v[j] = bf2f(a8[j]) + bf2f(b8[j]) + bf2f(c8[j]);
        s += v[j]; sq += v[j] * v[j];
    }
    #pragma unroll
    for (int d = 1; d < 64; d <<= 1) {
        s  += __shfl_xor(s,  d, 64);
        sq += __shfl_xor(sq, d, 64);
    }
    float mean = s * (1.f / HIDDEN);
    float var  = sq * (1.f / HIDDEN) - mean * mean;
    float rstd = rsqrtf(var + 1e-5f);
    float o[8];
    #pragma unroll
    for (int j = 0; j < 8; ++j) {
        int col = lane * 8 + j;
        o[j] = (v[j] - mean) * rstd * g[col] + bb[col];
    }
    float4 o0 = {o[0], o[1], o[2], o[3]};
    float4 o1 = {o[4], o[5], o[6], o[7]};
    *(float4*)&of[off]     = o0;
    *(float4*)&of[off + 4] = o1;
}

// ---------------------------------------------------------------- launcher
extern "C" void kernel_launch(void* const* d_in, const int* in_sizes, int n_in,
                              void* d_out, int out_size, void* d_ws, size_t ws_size,
                              hipStream_t stream) {
    const float* x     = (const float*)d_in[0];
    const float* w_qkv = (const float*)d_in[1];
    const float* b_qkv = (const float*)d_in[2];
    const float* w_out = (const float*)d_in[3];
    const float* b_out = (const float*)d_in[4];
    const float* ln1_g = (const float*)d_in[5];
    const float* ln1_b = (const float*)d_in[6];
    const float* ln2_g = (const float*)d_in[7];
    const float* ln2_b = (const float*)d_in[8];
    const float* w1    = (const float*)d_in[9];
    const float* b1    = (const float*)d_in[10];
    const float* w2    = (const float*)d_in[11];
    const float* b2    = (const float*)d_in[12];
    const float* rel   = (const float*)d_in[13];
    float* out = (float*)d_out;

    char* ws = (char*)d_ws;
    bf16*  xb     = (bf16*)(ws + 0);
    bf16*  wqkv_t = (bf16*)(ws + 8388608);
    bf16*  wout_t = (bf16*)(ws + 9961472);
    bf16*  w1_t   = (bf16*)(ws + 10485760);
    bf16*  w2_t   = (bf16*)(ws + 12582912);
    bf16*  qkv    = (bf16*)(ws + 14680064);
    bf16*  v_t    = (bf16*)(ws + 39845888);
    bf16*  attn_o = (bf16*)(ws + 48234496);
    bf16*  proj   = (bf16*)(ws + 56623104);   // p0; p1 follows contiguously
    bf16*  h      = (bf16*)(ws + 14680064);   // reuses qkv+v_t (dead after attention)
    bf16*  x1b    = (bf16*)(ws + 90177536);

    // 1. fused prep: cast + all weight transposes
    prep_kernel<<<7168, 256, 0, stream>>>(x, w_qkv, w_out, w1, w2,
                                          xb, wqkv_t, wout_t, w1_t, w2_t);
    // 2. qkv projection (V blocks write v_t directly)
    gemm_kernel<0,128,1,0,0><<<dim3(MM/128, 1536/128), 256, 0, stream>>>(
        xb, wqkv_t, b_qkv, nullptr, qkv, v_t, MM, 1536, 512);
    // 3. flash attention (128 q-rows per block, 2 kv-groups x 4 waves x 32q)
    attn_kernel<<<dim3(TT/128, BB*HEADS), 512, 0, stream>>>(qkv, v_t, rel, attn_o);
    // 4. output projection + residual(x, f32) -> bf16
    gemm_kernel<0,64,0,1,0><<<dim3(MM/128, 512/64), 256, 0, stream>>>(
        attn_o, wout_t, b_out, x, proj, nullptr, MM, 512, 512);
    // 5. LN1 -> x1b (bf16)
    ln_kernel<1><<<MM/4, 256, 0, stream>>>(proj, ln1_g, ln1_b, nullptr, x1b);
    // 6. MLP up + GELU(tanh) -> h (bf16), 128x128 tile
    gemm_kernel<2,128,0,0,0><<<dim3(MM/128, 2048/128), 256, 0, stream>>>(
        x1b, w1_t, b1, nullptr, h, nullptr, MM, 2048, 512);
    // 7. MLP down, split-K x2 -> bf16 partials p0/p1 (bias in z=1)
    gemm_kernel<0,64,0,0,1><<<dim3(MM/128, 512/64, 2), 256, 0, stream>>>(
        h, w2_t, b2, nullptr, proj, nullptr, MM, 512, 2048);
    // 8. LN2 over (x1b + p0 + p1) -> output (f32)
    ln3_kernel<<<MM/4, 256, 0, stream>>>(x1b, proj, proj + (size_t)MM*512,
                                         ln2_g, ln2_b, out);
}